// Round 11
// baseline (491.331 us; speedup 1.0000x reference)
//
#include <hip/hip_runtime.h>
#include <math.h>

#define DQ 2048
#define CDIM 512
#define NKEYS 256
#define KSEL 32

__device__ __forceinline__ bool rank_before(float as, int ai, float bs, int bi) {
  return (as > bs) || (as == bs && ai < bi);
}
static __device__ __forceinline__ float bf2f(unsigned int u) {
  union { unsigned int i; float f; } v; v.i = u << 16; return v.f;
}
static __device__ __forceinline__ unsigned int f2bf(float f) {
  union { float f; unsigned int i; } v; v.f = f;
  unsigned int r = v.i + 0x7fffu + ((v.i >> 16) & 1u);
  return r >> 16;
}

// ---------------- q = LN(X * Wq^T) fused (fp32 vector GEMM + groupwise LN) ----------------
// Round-11: double-buffered LDS. Same 64x128 tile / grid 32x16 (r9's retile-down
// REGRESSED; do not revisit). Change: two LDS buffer sets; write tile k+1 into
// buf^1 while computing buf -> ONE barrier per K-tile (32 total) instead of two
// (64). FMA order identical -> bit-exact output.
__global__ __launch_bounds__(256) void qgemm_ln(
    const float* __restrict__ X, const float* __restrict__ W,
    const float* __restrict__ gamma, const float* __restrict__ beta,
    float* __restrict__ Q) {
  __shared__ float As[2 * 16 * 68];   // [buf][k][m]
  __shared__ float Bs[2 * 16 * 132];  // [buf][k][n]
  const int tid = threadIdx.x;
  const int m0 = blockIdx.x * 64, n0 = blockIdx.y * 128;
  const int tx = tid & 15, ty = tid >> 4;
  const int am = tid >> 2, ak = (tid & 3) * 4;
  const int bn = tid >> 1, bk = (tid & 1) * 8;
  float acc[4][8] = {};
  // stage tile 0 into buf 0
  {
    float4 av  = *(const float4*)&X[(size_t)(m0 + am) * CDIM + ak];
    float4 bv0 = *(const float4*)&W[(size_t)(n0 + bn) * CDIM + bk];
    float4 bv1 = *(const float4*)&W[(size_t)(n0 + bn) * CDIM + bk + 4];
    As[(ak + 0) * 68 + am] = av.x; As[(ak + 1) * 68 + am] = av.y;
    As[(ak + 2) * 68 + am] = av.z; As[(ak + 3) * 68 + am] = av.w;
    Bs[(bk + 0) * 132 + bn] = bv0.x; Bs[(bk + 1) * 132 + bn] = bv0.y;
    Bs[(bk + 2) * 132 + bn] = bv0.z; Bs[(bk + 3) * 132 + bn] = bv0.w;
    Bs[(bk + 4) * 132 + bn] = bv1.x; Bs[(bk + 5) * 132 + bn] = bv1.y;
    Bs[(bk + 6) * 132 + bn] = bv1.z; Bs[(bk + 7) * 132 + bn] = bv1.w;
  }
  __syncthreads();
  int cur = 0;
  for (int kt = 0; kt < CDIM; kt += 16) {
    const bool more = (kt + 16 < CDIM);
    float4 av, bv0, bv1;
    if (more) {  // issue next-tile loads early; latency hides under compute
      av  = *(const float4*)&X[(size_t)(m0 + am) * CDIM + kt + 16 + ak];
      bv0 = *(const float4*)&W[(size_t)(n0 + bn) * CDIM + kt + 16 + bk];
      bv1 = *(const float4*)&W[(size_t)(n0 + bn) * CDIM + kt + 16 + bk + 4];
    }
    const float* Ac = &As[cur * (16 * 68)];
    const float* Bc = &Bs[cur * (16 * 132)];
    #pragma unroll
    for (int kk = 0; kk < 16; ++kk) {
      float4 a4  = *(const float4*)&Ac[kk * 68 + ty * 4];
      float4 b4a = *(const float4*)&Bc[kk * 132 + tx * 8];
      float4 b4b = *(const float4*)&Bc[kk * 132 + tx * 8 + 4];
      const float ar[4] = {a4.x, a4.y, a4.z, a4.w};
      const float br[8] = {b4a.x, b4a.y, b4a.z, b4a.w, b4b.x, b4b.y, b4b.z, b4b.w};
      #pragma unroll
      for (int i = 0; i < 4; ++i)
        #pragma unroll
        for (int j = 0; j < 8; ++j)
          acc[i][j] += ar[i] * br[j];
    }
    if (more) {  // write next tile to the other buffer; one barrier per tile
      float* An = &As[(cur ^ 1) * (16 * 68)];
      float* Bn = &Bs[(cur ^ 1) * (16 * 132)];
      An[(ak + 0) * 68 + am] = av.x; An[(ak + 1) * 68 + am] = av.y;
      An[(ak + 2) * 68 + am] = av.z; An[(ak + 3) * 68 + am] = av.w;
      Bn[(bk + 0) * 132 + bn] = bv0.x; Bn[(bk + 1) * 132 + bn] = bv0.y;
      Bn[(bk + 2) * 132 + bn] = bv0.z; Bn[(bk + 3) * 132 + bn] = bv0.w;
      Bn[(bk + 4) * 132 + bn] = bv1.x; Bn[(bk + 5) * 132 + bn] = bv1.y;
      Bn[(bk + 6) * 132 + bn] = bv1.z; Bn[(bk + 7) * 132 + bn] = bv1.w;
      __syncthreads();
      cur ^= 1;
    }
  }
  float g[8], bta[8];
  #pragma unroll
  for (int j = 0; j < 8; ++j) { g[j] = gamma[tx * 8 + j]; bta[j] = beta[tx * 8 + j]; }
  #pragma unroll
  for (int i = 0; i < 4; ++i) {
    float s = 0.f, sq = 0.f;
    #pragma unroll
    for (int j = 0; j < 8; ++j) { s += acc[i][j]; sq += acc[i][j] * acc[i][j]; }
    #pragma unroll
    for (int m = 1; m < 16; m <<= 1) {
      s += __shfl_xor(s, m, 64);
      sq += __shfl_xor(sq, m, 64);
    }
    float mean = s * (1.0f / 128.0f);
    float var = sq * (1.0f / 128.0f) - mean * mean;
    float rs = 1.0f / sqrtf(var + 1e-5f);
    float o[8];
    #pragma unroll
    for (int j = 0; j < 8; ++j) o[j] = (acc[i][j] - mean) * rs * g[j] + bta[j];
    float* dst = &Q[(size_t)(m0 + ty * 4 + i) * DQ + n0 + tx * 8];
    *(float4*)dst = make_float4(o[0], o[1], o[2], o[3]);
    *(float4*)(dst + 4) = make_float4(o[4], o[5], o[6], o[7]);
  }
}

// ---------------- keys[h][n][p][d] -> keysT[hp][d][n] (one-time, 2 MB) ----------------
__global__ __launch_bounds__(256) void transpose_keys(
    const float* __restrict__ keys, float* __restrict__ keysT) {
  __shared__ float tile[64 * 129];
  const int hp = blockIdx.x, h = hp >> 1, p = hp & 1;
  const int n0 = blockIdx.y * 64;
  {
    const int n = threadIdx.x >> 2;          // 0..63
    const int d0 = (threadIdx.x & 3) * 32;   // 0,32,64,96
    const float* src = &keys[(((size_t)h * NKEYS + n0 + n) * 2 + p) * 128 + d0];
    #pragma unroll
    for (int j = 0; j < 32; j += 4) {
      float4 v = *(const float4*)(src + j);
      tile[n * 129 + d0 + j + 0] = v.x;
      tile[n * 129 + d0 + j + 1] = v.y;
      tile[n * 129 + d0 + j + 2] = v.z;
      tile[n * 129 + d0 + j + 3] = v.w;
    }
  }
  __syncthreads();
  {
    const int d = threadIdx.x >> 1;          // 0..127
    const int nh = (threadIdx.x & 1) * 32;   // 0,32
    float* dst = &keysT[((size_t)hp * 128 + d) * NKEYS + n0 + nh];
    #pragma unroll
    for (int j = 0; j < 32; j += 4) {
      float4 o = make_float4(tile[(nh + j + 0) * 129 + d], tile[(nh + j + 1) * 129 + d],
                             tile[(nh + j + 2) * 129 + d], tile[(nh + j + 3) * 129 + d]);
      *(float4*)(dst + j) = o;
    }
  }
}

// ---------------- dots (A uniform from global/SMEM, B coalesced from global/L2) ----------
// FROZEN at the round-5 structure (104 us, best measured). Ledger of failed
// alternatives -- do not revisit:
//   * blocked-layout sort through LDS (r1-2): 166 us, VALU-throughput-bound
//   * key-only sort + ballot id recovery (r6-7): 131 us, serial readlane chain
//   * 4-way interleave (r8): 122 us, compiler serializes at ~36 VGPRs
// Zero LDS, zero barriers; A rows wave-uniform via readfirstlane -> s_load;
// B from keysT d-major, coalesced 1KB wave-loads, L2-hot. Sort = 2-pair
// interleaved payload bitonic. launch_bounds (512,5): VGPR cap ~102
// ((512,6)'s 80-cap demoted sort state to scratch in round 1).
__global__ __launch_bounds__(512, 5) void dots_sel(
    const float* __restrict__ Q, const float* __restrict__ keysT,
    float* __restrict__ s1s, int* __restrict__ s1i) {
  const int hp = blockIdx.x;
  const int chunk = blockIdx.y;
  const int h = hp >> 1, p = hp & 1;
  const int t0 = chunk * 32;
  const int tid = threadIdx.x;
  const int w = tid >> 6, lane = tid & 63;
  // wave-uniform Q row pointers (readfirstlane -> provably uniform -> SMEM)
  const int wu = __builtin_amdgcn_readfirstlane(w);
  const float* q0 = &Q[(size_t)(t0 + wu * 4 + 0) * DQ + p * 1024 + h * 128];
  const float* q1 = q0 + DQ;
  const float* q2 = q0 + 2 * DQ;
  const float* q3 = q0 + 3 * DQ;
  const float* kT = keysT + (size_t)hp * 128 * NKEYS + lane * 4;
  float acc[4][4] = {};
  #pragma unroll 2
  for (int kt = 0; kt < 128; kt += 4) {
    float4 a0 = *(const float4*)&q0[kt];
    float4 a1 = *(const float4*)&q1[kt];
    float4 a2 = *(const float4*)&q2[kt];
    float4 a3 = *(const float4*)&q3[kt];
    const float a0r[4] = {a0.x, a0.y, a0.z, a0.w};
    const float a1r[4] = {a1.x, a1.y, a1.z, a1.w};
    const float a2r[4] = {a2.x, a2.y, a2.z, a2.w};
    const float a3r[4] = {a3.x, a3.y, a3.z, a3.w};
    #pragma unroll
    for (int kk = 0; kk < 4; ++kk) {
      float4 b4 = *(const float4*)&kT[(size_t)(kt + kk) * NKEYS];
      const float br[4] = {b4.x, b4.y, b4.z, b4.w};
      #pragma unroll
      for (int j = 0; j < 4; ++j) {
        acc[0][j] += a0r[kk] * br[j];
        acc[1][j] += a1r[kk] * br[j];
        acc[2][j] += a2r[kk] * br[j];
        acc[3][j] += a3r[kk] * br[j];
      }
    }
  }
  // ---- paired in-register bitonic top-32 (2 concurrent sorts per iteration)
  #define CE1(S, I, a, b, dd)                                                  \
    {                                                                          \
      bool sw_ = (dd) ? rank_before(S[a], I[a], S[b], I[b])                    \
                      : rank_before(S[b], I[b], S[a], I[a]);                   \
      if (sw_) {                                                               \
        float ts_ = S[a]; S[a] = S[b]; S[b] = ts_;                             \
        int ti_ = I[a]; I[a] = I[b]; I[b] = ti_;                               \
      }                                                                        \
    }
  #define CEP(a, b, dd) { CE1(sA, iA, a, b, dd) CE1(sB, iB, a, b, dd) }
  #define CROSSP(L, dd)                                                        \
    {                                                                          \
      bool amHigh = (lane & (L)) != 0;                                         \
      bool flip = amHigh != (dd);                                              \
      _Pragma("unroll")                                                        \
      for (int r = 0; r < 4; ++r) {                                            \
        float osA = __shfl_xor(sA[r], (L), 64);                                \
        int oiA = __shfl_xor(iA[r], (L), 64);                                  \
        float osB = __shfl_xor(sB[r], (L), 64);                                \
        int oiB = __shfl_xor(iB[r], (L), 64);                                  \
        bool tA = rank_before(osA, oiA, sA[r], iA[r]) != flip;                 \
        if (tA) { sA[r] = osA; iA[r] = oiA; }                                  \
        bool tB = rank_before(osB, oiB, sB[r], iB[r]) != flip;                 \
        if (tB) { sB[r] = osB; iB[r] = oiB; }                                  \
      }                                                                        \
    }
  #pragma unroll
  for (int ii = 0; ii < 4; ii += 2) {  // fully unrolled: acc indexing stays static
    float sA[4], sB[4]; int iA[4], iB[4];
    #pragma unroll
    for (int r = 0; r < 4; ++r) {
      sA[r] = acc[ii][r];     iA[r] = lane * 4 + r;
      sB[r] = acc[ii + 1][r]; iB[r] = lane * 4 + r;
    }
    CEP(0, 1, false); CEP(2, 3, true);
    {
      bool dd = (lane & 1) != 0;
      CEP(0, 2, dd); CEP(1, 3, dd); CEP(0, 1, dd); CEP(2, 3, dd);
    }
    #pragma unroll
    for (int K = 8; K <= 256; K <<= 1) {
      bool dd = (lane & (K >> 2)) != 0;
      #pragma unroll
      for (int L = K >> 3; L >= 1; L >>= 1) CROSSP(L, dd);
      CEP(0, 2, dd); CEP(1, 3, dd); CEP(0, 1, dd); CEP(2, 3, dd);
    }
    const int instA = (t0 + w * 4 + ii) * 16 + hp;
    const int instB = instA + 16;  // token ii+1
    if (lane < 8) {
      *(float4*)&s1s[(size_t)instA * KSEL + lane * 4] = make_float4(sA[0], sA[1], sA[2], sA[3]);
      *(int4*)&s1i[(size_t)instA * KSEL + lane * 4] = make_int4(iA[0], iA[1], iA[2], iA[3]);
      *(float4*)&s1s[(size_t)instB * KSEL + lane * 4] = make_float4(sB[0], sB[1], sB[2], sB[3]);
      *(int4*)&s1i[(size_t)instB * KSEL + lane * 4] = make_int4(iB[0], iB[1], iB[2], iB[3]);
    }
  }
  #undef CE1
  #undef CEP
  #undef CROSSP
}

// ---------------- stage-2 candidate table (shared by fused + fallback) ----------------
__constant__ unsigned short slot_ij[128] = {
  0,1,2,3,4,5,6,7,8,9,10,11,12,13,14,15,16,17,18,19,20,21,22,23,24,25,26,27,28,29,30,31,
  32,33,34,35,36,37,38,39,40,41,42,43,44,45,46,47,
  64,65,66,67,68,69,70,71,72,73,
  96,97,98,99,100,101,102,103,
  128,129,130,131,132,133,
  160,161,162,163,164,
  192,193,194,195,
  224,225,226,227,
  256,257,258,
  288,289,290,
  320,321, 352,353, 384,385, 416,417, 448,449, 480,481,
  512,544,576,608,640,672,704,736,768,800,832,864,896,928,960,992,
  0xFFFF,0xFFFF,0xFFFF,0xFFFF,0xFFFF,0xFFFF,0xFFFF,0xFFFF,0xFFFF
};

// ---------------- FUSED stage-2 + gather (bf16 path) ----------------
// Round-10 fusion kept (matched best-known with one fewer dispatch).
// Round-11 change: gather phases 4 -> 16. 4-phase slices were 8 MB (> 4 MB
// per-XCD L2, thrash to L3); 16-phase slices are 4 MB and L2-resident, cutting
// the 512 MB of row reads from L3-BW to mostly L2-BW. Extra cost: e-loop runs
// 1024 wave-uniform skip iterations instead of 256 (~2 us).
__global__ __launch_bounds__(256) void stage2_gather(
    const float* __restrict__ s1s, const int* __restrict__ s1i,
    const unsigned short* __restrict__ vbf, float* __restrict__ out) {
  const int t = blockIdx.x;
  const int tid = threadIdx.x, w = tid >> 6, lane = tid & 63;
  __shared__ float ws_[256];
  __shared__ int vs_[256];
  __shared__ float part[4 * 520];
  // ---- stage-2 for hA = 2w, hB = 2w+1 (two interleaved instances per wave)
  {
    const int thA = t * 8 + w * 2;
    const int bxA = thA * 64, byA = bxA + 32;
    const int bxB = bxA + 64, byB = bxA + 96;
    float sA[2], sB[2]; int idA[2], idB[2];
    #pragma unroll
    for (int r = 0; r < 2; ++r) {
      int sl = slot_ij[lane * 2 + r];
      if (sl != 0xFFFF) {
        sA[r] = s1s[bxA + (sl >> 5)] + s1s[byA + (sl & 31)];
        sB[r] = s1s[bxB + (sl >> 5)] + s1s[byB + (sl & 31)];
        idA[r] = sl; idB[r] = sl;
      } else {
        sA[r] = -INFINITY; idA[r] = 0x7fffffff;
        sB[r] = -INFINITY; idB[r] = 0x7fffffff;
      }
    }
    #define CE2I(S, I, dd)                                                     \
      {                                                                        \
        bool sw = (dd) ? rank_before(S[0], I[0], S[1], I[1])                   \
                       : rank_before(S[1], I[1], S[0], I[0]);                  \
        if (sw) {                                                              \
          float ts = S[0]; S[0] = S[1]; S[1] = ts;                             \
          int ti = I[0]; I[0] = I[1]; I[1] = ti;                               \
        }                                                                      \
      }
    #define CE2P(dd) { CE2I(sA, idA, dd) CE2I(sB, idB, dd) }
    #define CROSS2P(L, dd)                                                     \
      {                                                                        \
        bool amHigh = (lane & (L)) != 0;                                       \
        bool flip = amHigh != (dd);                                            \
        _Pragma("unroll")                                                      \
        for (int r = 0; r < 2; ++r) {                                          \
          float osA = __shfl_xor(sA[r], (L), 64);                              \
          int oiA = __shfl_xor(idA[r], (L), 64);                               \
          float osB = __shfl_xor(sB[r], (L), 64);                              \
          int oiB = __shfl_xor(idB[r], (L), 64);                               \
          bool tA = rank_before(osA, oiA, sA[r], idA[r]) != flip;              \
          if (tA) { sA[r] = osA; idA[r] = oiA; }                               \
          bool tB = rank_before(osB, oiB, sB[r], idB[r]) != flip;              \
          if (tB) { sB[r] = osB; idB[r] = oiB; }                               \
        }                                                                      \
      }
    { bool dd = (lane & 1) != 0; CE2P(dd); }
    #pragma unroll
    for (int K = 4; K <= 128; K <<= 1) {
      bool dd = (lane & (K >> 1)) != 0;
      #pragma unroll
      for (int L = K >> 2; L >= 1; L >>= 1) CROSS2P(L, dd);
      CE2P(dd);
    }
    #undef CE2I
    #undef CE2P
    #undef CROSS2P
    float smA = __shfl(sA[0], 0, 64);
    float smB = __shfl(sB[0], 0, 64);
    float eA0 = 0.f, eA1 = 0.f, eB0 = 0.f, eB1 = 0.f;
    if (lane < 16) {
      eA0 = expf(sA[0] - smA); eA1 = expf(sA[1] - smA);
      eB0 = expf(sB[0] - smB); eB1 = expf(sB[1] - smB);
    }
    float pA = eA0 + eA1, pB = eB0 + eB1;
    #pragma unroll
    for (int m = 1; m < 16; m <<= 1) {
      pA += __shfl_xor(pA, m, 64);
      pB += __shfl_xor(pB, m, 64);
    }
    if (lane < 16) {
      const int fA0 = idA[0], fA1 = idA[1], fB0 = idB[0], fB1 = idB[1];
      const int viA0 = s1i[bxA + (fA0 >> 5)] * NKEYS + s1i[byA + (fA0 & 31)];
      const int viA1 = s1i[bxA + (fA1 >> 5)] * NKEYS + s1i[byA + (fA1 & 31)];
      const int viB0 = s1i[bxB + (fB0 >> 5)] * NKEYS + s1i[byB + (fB0 & 31)];
      const int viB1 = s1i[bxB + (fB1 >> 5)] * NKEYS + s1i[byB + (fB1 & 31)];
      const int eoA = (w * 2) * 32 + lane * 2;   // entry index h*32 + j
      const int eoB = eoA + 32;
      ws_[eoA] = eA0 / pA; ws_[eoA + 1] = eA1 / pA;
      vs_[eoA] = viA0;     vs_[eoA + 1] = viA1;
      ws_[eoB] = eB0 / pB; ws_[eoB + 1] = eB1 / pB;
      vs_[eoB] = viB0;     vs_[eoB + 1] = viB1;
    }
  }
  __syncthreads();
  // ---- gather: wave-per-row, 16 L2-resident phases (4 MB slice each)
  float acc[8] = {};
  const int c0 = lane * 8;
  #pragma unroll 1
  for (int phase = 0; phase < 16; ++phase) {
    for (int e = w; e < 256; e += 4) {
      const int row = vs_[e];                 // wave-uniform scalar
      if ((row >> 12) != phase) continue;     // uniform branch, no divergence
      const float wv = ws_[e];
      uint4 pk = *(const uint4*)(vbf + (size_t)row * CDIM + c0);
      acc[0] += wv * bf2f(pk.x & 0xffff); acc[1] += wv * bf2f(pk.x >> 16);
      acc[2] += wv * bf2f(pk.y & 0xffff); acc[3] += wv * bf2f(pk.y >> 16);
      acc[4] += wv * bf2f(pk.z & 0xffff); acc[5] += wv * bf2f(pk.z >> 16);
      acc[6] += wv * bf2f(pk.w & 0xffff); acc[7] += wv * bf2f(pk.w >> 16);
    }
  }
  #pragma unroll
  for (int j = 0; j < 8; j += 4)
    *(float4*)&part[w * 520 + c0 + j] =
        make_float4(acc[j], acc[j + 1], acc[j + 2], acc[j + 3]);
  __syncthreads();
  const int c2 = tid * 2;
  float r0 = part[c2] + part[520 + c2] + part[1040 + c2] + part[1560 + c2];
  float r1 = part[c2 + 1] + part[520 + c2 + 1] + part[1040 + c2 + 1] + part[1560 + c2 + 1];
  *(float2*)(out + (size_t)t * CDIM + c2) = make_float2(r0, r1);
}

// ---------------- standalone stage-2 (fallback path only) ----------------
__global__ __launch_bounds__(256) void stage2_kernel(
    const float* __restrict__ s1s, const int* __restrict__ s1i,
    float* __restrict__ wgt, int* __restrict__ vidx) {
  const int th = blockIdx.x * 4 + (threadIdx.x >> 6);
  const int lane = threadIdx.x & 63;
  const int bx = th * 64;
  const int by = bx + 32;
  float s[2]; int id[2];
  #pragma unroll
  for (int r = 0; r < 2; ++r) {
    int sl = slot_ij[lane * 2 + r];
    if (sl != 0xFFFF) {
      s[r] = s1s[bx + (sl >> 5)] + s1s[by + (sl & 31)];
      id[r] = sl;
    } else {
      s[r] = -INFINITY; id[r] = 0x7fffffff;
    }
  }
  #define CE2(dd)                                                              \
    {                                                                          \
      bool sw = (dd) ? rank_before(s[0], id[0], s[1], id[1])                   \
                     : rank_before(s[1], id[1], s[0], id[0]);                  \
      if (sw) {                                                                \
        float ts = s[0]; s[0] = s[1]; s[1] = ts;                               \
        int ti = id[0]; id[0] = id[1]; id[1] = ti;                             \
      }                                                                        \
    }
  #define CROSS2(L, dd)                                                        \
    {                                                                          \
      bool amHigh = (lane & (L)) != 0;                                         \
      bool flip = amHigh != (dd);                                              \
      _Pragma("unroll")                                                        \
      for (int r = 0; r < 2; ++r) {                                            \
        float os = __shfl_xor(s[r], (L), 64);                                  \
        int oi = __shfl_xor(id[r], (L), 64);                                   \
        bool take = rank_before(os, oi, s[r], id[r]) != flip;                  \
        if (take) { s[r] = os; id[r] = oi; }                                   \
      }                                                                        \
    }
  { bool dd = (lane & 1) != 0; CE2(dd); }
  #pragma unroll
  for (int K = 4; K <= 128; K <<= 1) {
    bool dd = (lane & (K >> 1)) != 0;
    #pragma unroll
    for (int L = K >> 2; L >= 1; L >>= 1) CROSS2(L, dd);
    CE2(dd);
  }
  #undef CE2
  #undef CROSS2
  float smax = __shfl(s[0], 0, 64);
  float e0 = 0.f, e1 = 0.f;
  if (lane < 16) { e0 = expf(s[0] - smax); e1 = expf(s[1] - smax); }
  float part = e0 + e1;
  #pragma unroll
  for (int m = 1; m < 16; m <<= 1) part += __shfl_xor(part, m, 64);
  if (lane < 16) {
    int f0 = id[0], f1 = id[1];
    int vi0 = s1i[bx + (f0 >> 5)] * NKEYS + s1i[by + (f0 & 31)];
    int vi1 = s1i[bx + (f1 >> 5)] * NKEYS + s1i[by + (f1 & 31)];
    wgt[(size_t)th * KSEL + lane * 2] = e0 / part;
    wgt[(size_t)th * KSEL + lane * 2 + 1] = e1 / part;
    vidx[(size_t)th * KSEL + lane * 2] = vi0;
    vidx[(size_t)th * KSEL + lane * 2 + 1] = vi1;
  }
}

// ---------------- values fp32 -> bf16 (RNE) one-pass convert ----------------
__global__ __launch_bounds__(256) void convert_values(
    const float* __restrict__ values, unsigned int* __restrict__ vbf) {
  const size_t g = ((size_t)blockIdx.x * 256 + threadIdx.x) * 8;
  float4 a = *(const float4*)(values + g);
  float4 b = *(const float4*)(values + g + 4);
  uint4 pk;
  pk.x = f2bf(a.x) | (f2bf(a.y) << 16);
  pk.y = f2bf(a.z) | (f2bf(a.w) << 16);
  pk.z = f2bf(b.x) | (f2bf(b.y) << 16);
  pk.w = f2bf(b.z) | (f2bf(b.w) << 16);
  *(uint4*)(vbf + g / 2) = pk;
}

// ---------------- fallback fp32 gather (for small ws) ----------------
__global__ __launch_bounds__(256) void gather_kernel(
    const float* __restrict__ wgt, const int* __restrict__ vidx,
    const float* __restrict__ values, float* __restrict__ out) {
  const int tp = blockIdx.x;
  const int tid = threadIdx.x;
  __shared__ float ws_[512];
  __shared__ int vs_[512];
  ws_[tid] = wgt[(size_t)tp * 512 + tid];
  ws_[tid + 256] = wgt[(size_t)tp * 512 + tid + 256];
  vs_[tid] = vidx[(size_t)tp * 512 + tid];
  vs_[tid + 256] = vidx[(size_t)tp * 512 + tid + 256];
  __syncthreads();
  const int sub = tid >> 7;
  const int c4 = (tid & 127) * 4;
  const float* wp = &ws_[sub * 256];
  const int* vp = &vs_[sub * 256];
  float4 a = make_float4(0.f, 0.f, 0.f, 0.f);
  #pragma unroll 4
  for (int e = 0; e < 256; ++e) {
    float4 vv = *(const float4*)(values + (size_t)vp[e] * CDIM + c4);
    float wv = wp[e];
    a.x += wv * vv.x; a.y += wv * vv.y; a.z += wv * vv.z; a.w += wv * vv.w;
  }
  *(float4*)(out + (size_t)(tp * 2 + sub) * CDIM + c4) = a;
}

extern "C" void kernel_launch(void* const* d_in, const int* in_sizes, int n_in,
                              void* d_out, int out_size, void* d_ws, size_t ws_size,
                              hipStream_t stream) {
  const float* X      = (const float*)d_in[0];
  const float* W      = (const float*)d_in[1];
  const float* keys   = (const float*)d_in[2];
  const float* values = (const float*)d_in[3];
  const float* gamma  = (const float*)d_in[4];
  const float* beta   = (const float*)d_in[5];
  char* ws = (char*)d_ws;
  float* s1s = (float*)(ws);                  // 0..4 MB
  int*   s1i = (int*)  (ws + (4u << 20));     // 4..8 MB
  float* wgt = (float*)(ws + (8u << 20));     // 8..10 MB (fallback path only)
  int*   vix = (int*)  (ws + (10u << 20));    // 10..12 MB (fallback path only)
  float* Q   = (float*)(ws + (12u << 20));    // 12..28 MB (dead after dots_sel)
  float* kT  = (float*)(ws + (28u << 20));    // 28..30 MB (dead after dots_sel)
  unsigned int* vbf = (unsigned int*)(ws + (12u << 20));  // 12..76 MB (overlaps dead Q+kT)

  const bool bf16_path = ws_size >= (76u << 20);

  transpose_keys<<<dim3(16, 4), 256, 0, stream>>>(keys, kT);
  qgemm_ln<<<dim3(32, 16), 256, 0, stream>>>(X, W, gamma, beta, Q);
  dots_sel<<<dim3(16, 64), 512, 0, stream>>>(Q, kT, s1s, s1i);
  if (bf16_path) {
    convert_values<<<16384, 256, 0, stream>>>(values, vbf);  // after dots_sel: Q,kT dead
    stage2_gather<<<2048, 256, 0, stream>>>(s1s, s1i, (const unsigned short*)vbf, (float*)d_out);
  } else {
    stage2_kernel<<<4096, 256, 0, stream>>>(s1s, s1i, wgt, vix);
    gather_kernel<<<1024, 256, 0, stream>>>(wgt, vix, values, (float*)d_out);
  }
}

// Round 12
// 402.569 us; speedup vs baseline: 1.2205x; 1.2205x over previous
//
#include <hip/hip_runtime.h>
#include <math.h>

#define DQ 2048
#define CDIM 512
#define NKEYS 256
#define KSEL 32

__device__ __forceinline__ bool rank_before(float as, int ai, float bs, int bi) {
  return (as > bs) || (as == bs && ai < bi);
}
static __device__ __forceinline__ float bf2f(unsigned int u) {
  union { unsigned int i; float f; } v; v.i = u << 16; return v.f;
}
static __device__ __forceinline__ unsigned int f2bf(float f) {
  union { float f; unsigned int i; } v; v.f = f;
  unsigned int r = v.i + 0x7fffu + ((v.i >> 16) & 1u);
  return r >> 16;
}

// ================= shared device bodies (used by fused + standalone) =================
__device__ __forceinline__ void qgemm_body(
    const float* __restrict__ X, const float* __restrict__ W,
    const float* __restrict__ gamma, const float* __restrict__ beta,
    float* __restrict__ Q, float* smem, int bx, int by, int tid) {
  float* As = smem;            // 16*68
  float* Bs = smem + 16 * 68;  // 16*132
  const int m0 = bx * 64, n0 = by * 128;
  const int tx = tid & 15, ty = tid >> 4;
  const int am = tid >> 2, ak = (tid & 3) * 4;
  const int bn = tid >> 1, bk = (tid & 1) * 8;
  float acc[4][8] = {};
  float4 av  = *(const float4*)&X[(size_t)(m0 + am) * CDIM + ak];
  float4 bv0 = *(const float4*)&W[(size_t)(n0 + bn) * CDIM + bk];
  float4 bv1 = *(const float4*)&W[(size_t)(n0 + bn) * CDIM + bk + 4];
  for (int kt = 0; kt < CDIM; kt += 16) {
    __syncthreads();
    As[(ak + 0) * 68 + am] = av.x; As[(ak + 1) * 68 + am] = av.y;
    As[(ak + 2) * 68 + am] = av.z; As[(ak + 3) * 68 + am] = av.w;
    Bs[(bk + 0) * 132 + bn] = bv0.x; Bs[(bk + 1) * 132 + bn] = bv0.y;
    Bs[(bk + 2) * 132 + bn] = bv0.z; Bs[(bk + 3) * 132 + bn] = bv0.w;
    Bs[(bk + 4) * 132 + bn] = bv1.x; Bs[(bk + 5) * 132 + bn] = bv1.y;
    Bs[(bk + 6) * 132 + bn] = bv1.z; Bs[(bk + 7) * 132 + bn] = bv1.w;
    __syncthreads();
    if (kt + 16 < CDIM) {
      av  = *(const float4*)&X[(size_t)(m0 + am) * CDIM + kt + 16 + ak];
      bv0 = *(const float4*)&W[(size_t)(n0 + bn) * CDIM + kt + 16 + bk];
      bv1 = *(const float4*)&W[(size_t)(n0 + bn) * CDIM + kt + 16 + bk + 4];
    }
    #pragma unroll
    for (int kk = 0; kk < 16; ++kk) {
      float4 a4  = *(const float4*)&As[kk * 68 + ty * 4];
      float4 b4a = *(const float4*)&Bs[kk * 132 + tx * 8];
      float4 b4b = *(const float4*)&Bs[kk * 132 + tx * 8 + 4];
      const float ar[4] = {a4.x, a4.y, a4.z, a4.w};
      const float br[8] = {b4a.x, b4a.y, b4a.z, b4a.w, b4b.x, b4b.y, b4b.z, b4b.w};
      #pragma unroll
      for (int i = 0; i < 4; ++i)
        #pragma unroll
        for (int j = 0; j < 8; ++j)
          acc[i][j] += ar[i] * br[j];
    }
  }
  float g[8], bta[8];
  #pragma unroll
  for (int j = 0; j < 8; ++j) { g[j] = gamma[tx * 8 + j]; bta[j] = beta[tx * 8 + j]; }
  #pragma unroll
  for (int i = 0; i < 4; ++i) {
    float s = 0.f, sq = 0.f;
    #pragma unroll
    for (int j = 0; j < 8; ++j) { s += acc[i][j]; sq += acc[i][j] * acc[i][j]; }
    #pragma unroll
    for (int m = 1; m < 16; m <<= 1) {
      s += __shfl_xor(s, m, 64);
      sq += __shfl_xor(sq, m, 64);
    }
    float mean = s * (1.0f / 128.0f);
    float var = sq * (1.0f / 128.0f) - mean * mean;
    float rs = 1.0f / sqrtf(var + 1e-5f);
    float o[8];
    #pragma unroll
    for (int j = 0; j < 8; ++j) o[j] = (acc[i][j] - mean) * rs * g[j] + bta[j];
    float* dst = &Q[(size_t)(m0 + ty * 4 + i) * DQ + n0 + tx * 8];
    *(float4*)dst = make_float4(o[0], o[1], o[2], o[3]);
    *(float4*)(dst + 4) = make_float4(o[4], o[5], o[6], o[7]);
  }
}

__device__ __forceinline__ void transpose_body(
    const float* __restrict__ keys, float* __restrict__ keysT,
    float* smem, int hp, int ny, int tid) {
  float* tile = smem;  // 64*129
  const int h = hp >> 1, p = hp & 1;
  const int n0 = ny * 64;
  {
    const int n = tid >> 2;
    const int d0 = (tid & 3) * 32;
    const float* src = &keys[(((size_t)h * NKEYS + n0 + n) * 2 + p) * 128 + d0];
    #pragma unroll
    for (int j = 0; j < 32; j += 4) {
      float4 v = *(const float4*)(src + j);
      tile[n * 129 + d0 + j + 0] = v.x;
      tile[n * 129 + d0 + j + 1] = v.y;
      tile[n * 129 + d0 + j + 2] = v.z;
      tile[n * 129 + d0 + j + 3] = v.w;
    }
  }
  __syncthreads();
  {
    const int d = tid >> 1;
    const int nh = (tid & 1) * 32;
    float* dst = &keysT[((size_t)hp * 128 + d) * NKEYS + n0 + nh];
    #pragma unroll
    for (int j = 0; j < 32; j += 4) {
      float4 o = make_float4(tile[(nh + j + 0) * 129 + d], tile[(nh + j + 1) * 129 + d],
                             tile[(nh + j + 2) * 129 + d], tile[(nh + j + 3) * 129 + d]);
      *(float4*)(dst + j) = o;
    }
  }
}

__device__ __forceinline__ void convert_body(
    const float* __restrict__ values, unsigned int* __restrict__ vbf, int cb, int tid) {
  const size_t g = ((size_t)cb * 256 + tid) * 8;
  float4 a = *(const float4*)(values + g);
  float4 b = *(const float4*)(values + g + 4);
  uint4 pk;
  pk.x = f2bf(a.x) | (f2bf(a.y) << 16);
  pk.y = f2bf(a.z) | (f2bf(a.w) << 16);
  pk.z = f2bf(b.x) | (f2bf(b.y) << 16);
  pk.w = f2bf(b.z) | (f2bf(b.w) << 16);
  *(uint4*)(vbf + g / 2) = pk;
}

// ---------------- FUSED pre-stage: qgemm + transpose + convert in one dispatch ----------------
// Round-12: the three pre-dots kernels are mutually independent. Block-range
// dispatch: qgemm blocks [0,512) issue first (the long pole, 2 blocks/CU);
// transpose [512,576) and convert [576,16960) fill idle CU slots and their
// memory traffic hides under qgemm's compute. Requires non-aliased vbf
// (convert runs concurrent with qgemm's Q writes) -> 92 MB layout; launcher
// falls back to the sequential r10 path when ws < 92 MB.
__global__ __launch_bounds__(256) void fused_pre(
    const float* __restrict__ X, const float* __restrict__ W,
    const float* __restrict__ gamma, const float* __restrict__ beta,
    float* __restrict__ Q,
    const float* __restrict__ keys, float* __restrict__ keysT,
    const float* __restrict__ values, unsigned int* __restrict__ vbf) {
  __shared__ float smem[64 * 129];  // max(qgemm 3200f, transpose 8256f)
  const int b = blockIdx.x;
  const int tid = threadIdx.x;
  if (b < 512) {
    qgemm_body(X, W, gamma, beta, Q, smem, b & 31, b >> 5, tid);
  } else if (b < 576) {
    const int idx = b - 512;
    transpose_body(keys, keysT, smem, idx & 15, idx >> 4, tid);
  } else {
    convert_body(values, vbf, b - 576, tid);
  }
}

// ---------------- standalone kernels (sequential fallback path, r10-exact) ----------------
__global__ __launch_bounds__(256) void qgemm_ln(
    const float* __restrict__ X, const float* __restrict__ W,
    const float* __restrict__ gamma, const float* __restrict__ beta,
    float* __restrict__ Q) {
  __shared__ float smem[16 * 68 + 16 * 132];
  qgemm_body(X, W, gamma, beta, Q, smem, blockIdx.x, blockIdx.y, threadIdx.x);
}

__global__ __launch_bounds__(256) void transpose_keys(
    const float* __restrict__ keys, float* __restrict__ keysT) {
  __shared__ float smem[64 * 129];
  transpose_body(keys, keysT, smem, blockIdx.x, blockIdx.y, threadIdx.x);
}

__global__ __launch_bounds__(256) void convert_values(
    const float* __restrict__ values, unsigned int* __restrict__ vbf) {
  convert_body(values, vbf, blockIdx.x, threadIdx.x);
}

// ---------------- dots (A uniform from global/SMEM, B coalesced from global/L2) ----------
// FROZEN at the round-5 structure (104 us, best measured). Ledger of failed
// alternatives -- do not revisit:
//   * blocked-layout sort through LDS (r1-2): 166 us, VALU-throughput-bound
//   * key-only sort + ballot id recovery (r6-7): 131 us, serial readlane chain
//   * 4-way interleave (r8): 122 us, compiler serializes at ~36 VGPRs
__global__ __launch_bounds__(512, 5) void dots_sel(
    const float* __restrict__ Q, const float* __restrict__ keysT,
    float* __restrict__ s1s, int* __restrict__ s1i) {
  const int hp = blockIdx.x;
  const int chunk = blockIdx.y;
  const int h = hp >> 1, p = hp & 1;
  const int t0 = chunk * 32;
  const int tid = threadIdx.x;
  const int w = tid >> 6, lane = tid & 63;
  const int wu = __builtin_amdgcn_readfirstlane(w);
  const float* q0 = &Q[(size_t)(t0 + wu * 4 + 0) * DQ + p * 1024 + h * 128];
  const float* q1 = q0 + DQ;
  const float* q2 = q0 + 2 * DQ;
  const float* q3 = q0 + 3 * DQ;
  const float* kT = keysT + (size_t)hp * 128 * NKEYS + lane * 4;
  float acc[4][4] = {};
  #pragma unroll 2
  for (int kt = 0; kt < 128; kt += 4) {
    float4 a0 = *(const float4*)&q0[kt];
    float4 a1 = *(const float4*)&q1[kt];
    float4 a2 = *(const float4*)&q2[kt];
    float4 a3 = *(const float4*)&q3[kt];
    const float a0r[4] = {a0.x, a0.y, a0.z, a0.w};
    const float a1r[4] = {a1.x, a1.y, a1.z, a1.w};
    const float a2r[4] = {a2.x, a2.y, a2.z, a2.w};
    const float a3r[4] = {a3.x, a3.y, a3.z, a3.w};
    #pragma unroll
    for (int kk = 0; kk < 4; ++kk) {
      float4 b4 = *(const float4*)&kT[(size_t)(kt + kk) * NKEYS];
      const float br[4] = {b4.x, b4.y, b4.z, b4.w};
      #pragma unroll
      for (int j = 0; j < 4; ++j) {
        acc[0][j] += a0r[kk] * br[j];
        acc[1][j] += a1r[kk] * br[j];
        acc[2][j] += a2r[kk] * br[j];
        acc[3][j] += a3r[kk] * br[j];
      }
    }
  }
  #define CE1(S, I, a, b, dd)                                                  \
    {                                                                          \
      bool sw_ = (dd) ? rank_before(S[a], I[a], S[b], I[b])                    \
                      : rank_before(S[b], I[b], S[a], I[a]);                   \
      if (sw_) {                                                               \
        float ts_ = S[a]; S[a] = S[b]; S[b] = ts_;                             \
        int ti_ = I[a]; I[a] = I[b]; I[b] = ti_;                               \
      }                                                                        \
    }
  #define CEP(a, b, dd) { CE1(sA, iA, a, b, dd) CE1(sB, iB, a, b, dd) }
  #define CROSSP(L, dd)                                                        \
    {                                                                          \
      bool amHigh = (lane & (L)) != 0;                                         \
      bool flip = amHigh != (dd);                                              \
      _Pragma("unroll")                                                        \
      for (int r = 0; r < 4; ++r) {                                            \
        float osA = __shfl_xor(sA[r], (L), 64);                                \
        int oiA = __shfl_xor(iA[r], (L), 64);                                  \
        float osB = __shfl_xor(sB[r], (L), 64);                                \
        int oiB = __shfl_xor(iB[r], (L), 64);                                  \
        bool tA = rank_before(osA, oiA, sA[r], iA[r]) != flip;                 \
        if (tA) { sA[r] = osA; iA[r] = oiA; }                                  \
        bool tB = rank_before(osB, oiB, sB[r], iB[r]) != flip;                 \
        if (tB) { sB[r] = osB; iB[r] = oiB; }                                  \
      }                                                                        \
    }
  #pragma unroll
  for (int ii = 0; ii < 4; ii += 2) {
    float sA[4], sB[4]; int iA[4], iB[4];
    #pragma unroll
    for (int r = 0; r < 4; ++r) {
      sA[r] = acc[ii][r];     iA[r] = lane * 4 + r;
      sB[r] = acc[ii + 1][r]; iB[r] = lane * 4 + r;
    }
    CEP(0, 1, false); CEP(2, 3, true);
    {
      bool dd = (lane & 1) != 0;
      CEP(0, 2, dd); CEP(1, 3, dd); CEP(0, 1, dd); CEP(2, 3, dd);
    }
    #pragma unroll
    for (int K = 8; K <= 256; K <<= 1) {
      bool dd = (lane & (K >> 2)) != 0;
      #pragma unroll
      for (int L = K >> 3; L >= 1; L >>= 1) CROSSP(L, dd);
      CEP(0, 2, dd); CEP(1, 3, dd); CEP(0, 1, dd); CEP(2, 3, dd);
    }
    const int instA = (t0 + w * 4 + ii) * 16 + hp;
    const int instB = instA + 16;
    if (lane < 8) {
      *(float4*)&s1s[(size_t)instA * KSEL + lane * 4] = make_float4(sA[0], sA[1], sA[2], sA[3]);
      *(int4*)&s1i[(size_t)instA * KSEL + lane * 4] = make_int4(iA[0], iA[1], iA[2], iA[3]);
      *(float4*)&s1s[(size_t)instB * KSEL + lane * 4] = make_float4(sB[0], sB[1], sB[2], sB[3]);
      *(int4*)&s1i[(size_t)instB * KSEL + lane * 4] = make_int4(iB[0], iB[1], iB[2], iB[3]);
    }
  }
  #undef CE1
  #undef CEP
  #undef CROSSP
}

// ---------------- stage-2 candidate table (shared by fused + fallback) ----------------
__constant__ unsigned short slot_ij[128] = {
  0,1,2,3,4,5,6,7,8,9,10,11,12,13,14,15,16,17,18,19,20,21,22,23,24,25,26,27,28,29,30,31,
  32,33,34,35,36,37,38,39,40,41,42,43,44,45,46,47,
  64,65,66,67,68,69,70,71,72,73,
  96,97,98,99,100,101,102,103,
  128,129,130,131,132,133,
  160,161,162,163,164,
  192,193,194,195,
  224,225,226,227,
  256,257,258,
  288,289,290,
  320,321, 352,353, 384,385, 416,417, 448,449, 480,481,
  512,544,576,608,640,672,704,736,768,800,832,864,896,928,960,992,
  0xFFFF,0xFFFF,0xFFFF,0xFFFF,0xFFFF,0xFFFF,0xFFFF,0xFFFF,0xFFFF
};

// ---------------- FUSED stage-2 + gather (bf16 path) ----------------
// Round-10 fusion kept. Gather phases REVERTED to 4 (r11's 16-phase split
// REGRESSED +36 us: 16 serial e-list passes collapsed memory-level
// parallelism; vbf slices gained no L2 residency. Ledger: phases>4 dead).
__global__ __launch_bounds__(256) void stage2_gather(
    const float* __restrict__ s1s, const int* __restrict__ s1i,
    const unsigned short* __restrict__ vbf, float* __restrict__ out) {
  const int t = blockIdx.x;
  const int tid = threadIdx.x, w = tid >> 6, lane = tid & 63;
  __shared__ float ws_[256];
  __shared__ int vs_[256];
  __shared__ float part[4 * 520];
  {
    const int thA = t * 8 + w * 2;
    const int bxA = thA * 64, byA = bxA + 32;
    const int bxB = bxA + 64, byB = bxA + 96;
    float sA[2], sB[2]; int idA[2], idB[2];
    #pragma unroll
    for (int r = 0; r < 2; ++r) {
      int sl = slot_ij[lane * 2 + r];
      if (sl != 0xFFFF) {
        sA[r] = s1s[bxA + (sl >> 5)] + s1s[byA + (sl & 31)];
        sB[r] = s1s[bxB + (sl >> 5)] + s1s[byB + (sl & 31)];
        idA[r] = sl; idB[r] = sl;
      } else {
        sA[r] = -INFINITY; idA[r] = 0x7fffffff;
        sB[r] = -INFINITY; idB[r] = 0x7fffffff;
      }
    }
    #define CE2I(S, I, dd)                                                     \
      {                                                                        \
        bool sw = (dd) ? rank_before(S[0], I[0], S[1], I[1])                   \
                       : rank_before(S[1], I[1], S[0], I[0]);                  \
        if (sw) {                                                              \
          float ts = S[0]; S[0] = S[1]; S[1] = ts;                             \
          int ti = I[0]; I[0] = I[1]; I[1] = ti;                               \
        }                                                                      \
      }
    #define CE2P(dd) { CE2I(sA, idA, dd) CE2I(sB, idB, dd) }
    #define CROSS2P(L, dd)                                                     \
      {                                                                        \
        bool amHigh = (lane & (L)) != 0;                                       \
        bool flip = amHigh != (dd);                                            \
        _Pragma("unroll")                                                      \
        for (int r = 0; r < 2; ++r) {                                          \
          float osA = __shfl_xor(sA[r], (L), 64);                              \
          int oiA = __shfl_xor(idA[r], (L), 64);                               \
          float osB = __shfl_xor(sB[r], (L), 64);                              \
          int oiB = __shfl_xor(idB[r], (L), 64);                               \
          bool tA = rank_before(osA, oiA, sA[r], idA[r]) != flip;              \
          if (tA) { sA[r] = osA; idA[r] = oiA; }                               \
          bool tB = rank_before(osB, oiB, sB[r], idB[r]) != flip;              \
          if (tB) { sB[r] = osB; idB[r] = oiB; }                               \
        }                                                                      \
      }
    { bool dd = (lane & 1) != 0; CE2P(dd); }
    #pragma unroll
    for (int K = 4; K <= 128; K <<= 1) {
      bool dd = (lane & (K >> 1)) != 0;
      #pragma unroll
      for (int L = K >> 2; L >= 1; L >>= 1) CROSS2P(L, dd);
      CE2P(dd);
    }
    #undef CE2I
    #undef CE2P
    #undef CROSS2P
    float smA = __shfl(sA[0], 0, 64);
    float smB = __shfl(sB[0], 0, 64);
    float eA0 = 0.f, eA1 = 0.f, eB0 = 0.f, eB1 = 0.f;
    if (lane < 16) {
      eA0 = expf(sA[0] - smA); eA1 = expf(sA[1] - smA);
      eB0 = expf(sB[0] - smB); eB1 = expf(sB[1] - smB);
    }
    float pA = eA0 + eA1, pB = eB0 + eB1;
    #pragma unroll
    for (int m = 1; m < 16; m <<= 1) {
      pA += __shfl_xor(pA, m, 64);
      pB += __shfl_xor(pB, m, 64);
    }
    if (lane < 16) {
      const int fA0 = idA[0], fA1 = idA[1], fB0 = idB[0], fB1 = idB[1];
      const int viA0 = s1i[bxA + (fA0 >> 5)] * NKEYS + s1i[byA + (fA0 & 31)];
      const int viA1 = s1i[bxA + (fA1 >> 5)] * NKEYS + s1i[byA + (fA1 & 31)];
      const int viB0 = s1i[bxB + (fB0 >> 5)] * NKEYS + s1i[byB + (fB0 & 31)];
      const int viB1 = s1i[bxB + (fB1 >> 5)] * NKEYS + s1i[byB + (fB1 & 31)];
      const int eoA = (w * 2) * 32 + lane * 2;
      const int eoB = eoA + 32;
      ws_[eoA] = eA0 / pA; ws_[eoA + 1] = eA1 / pA;
      vs_[eoA] = viA0;     vs_[eoA + 1] = viA1;
      ws_[eoB] = eB0 / pB; ws_[eoB + 1] = eB1 / pB;
      vs_[eoB] = viB0;     vs_[eoB + 1] = viB1;
    }
  }
  __syncthreads();
  // ---- gather: wave-per-row, 4 L3 phases (r10-proven)
  float acc[8] = {};
  const int c0 = lane * 8;
  #pragma unroll 1
  for (int phase = 0; phase < 4; ++phase) {
    for (int e = w; e < 256; e += 4) {
      const int row = vs_[e];
      if ((row >> 14) != phase) continue;
      const float wv = ws_[e];
      uint4 pk = *(const uint4*)(vbf + (size_t)row * CDIM + c0);
      acc[0] += wv * bf2f(pk.x & 0xffff); acc[1] += wv * bf2f(pk.x >> 16);
      acc[2] += wv * bf2f(pk.y & 0xffff); acc[3] += wv * bf2f(pk.y >> 16);
      acc[4] += wv * bf2f(pk.z & 0xffff); acc[5] += wv * bf2f(pk.z >> 16);
      acc[6] += wv * bf2f(pk.w & 0xffff); acc[7] += wv * bf2f(pk.w >> 16);
    }
  }
  #pragma unroll
  for (int j = 0; j < 8; j += 4)
    *(float4*)&part[w * 520 + c0 + j] =
        make_float4(acc[j], acc[j + 1], acc[j + 2], acc[j + 3]);
  __syncthreads();
  const int c2 = tid * 2;
  float r0 = part[c2] + part[520 + c2] + part[1040 + c2] + part[1560 + c2];
  float r1 = part[c2 + 1] + part[520 + c2 + 1] + part[1040 + c2 + 1] + part[1560 + c2 + 1];
  *(float2*)(out + (size_t)t * CDIM + c2) = make_float2(r0, r1);
}

// ---------------- standalone stage-2 (fp32 fallback path only) ----------------
__global__ __launch_bounds__(256) void stage2_kernel(
    const float* __restrict__ s1s, const int* __restrict__ s1i,
    float* __restrict__ wgt, int* __restrict__ vidx) {
  const int th = blockIdx.x * 4 + (threadIdx.x >> 6);
  const int lane = threadIdx.x & 63;
  const int bx = th * 64;
  const int by = bx + 32;
  float s[2]; int id[2];
  #pragma unroll
  for (int r = 0; r < 2; ++r) {
    int sl = slot_ij[lane * 2 + r];
    if (sl != 0xFFFF) {
      s[r] = s1s[bx + (sl >> 5)] + s1s[by + (sl & 31)];
      id[r] = sl;
    } else {
      s[r] = -INFINITY; id[r] = 0x7fffffff;
    }
  }
  #define CE2(dd)                                                              \
    {                                                                          \
      bool sw = (dd) ? rank_before(s[0], id[0], s[1], id[1])                   \
                     : rank_before(s[1], id[1], s[0], id[0]);                  \
      if (sw) {                                                                \
        float ts = s[0]; s[0] = s[1]; s[1] = ts;                               \
        int ti = id[0]; id[0] = id[1]; id[1] = ti;                             \
      }                                                                        \
    }
  #define CROSS2(L, dd)                                                        \
    {                                                                          \
      bool amHigh = (lane & (L)) != 0;                                         \
      bool flip = amHigh != (dd);                                              \
      _Pragma("unroll")                                                        \
      for (int r = 0; r < 2; ++r) {                                            \
        float os = __shfl_xor(s[r], (L), 64);                                  \
        int oi = __shfl_xor(id[r], (L), 64);                                   \
        bool take = rank_before(os, oi, s[r], id[r]) != flip;                  \
        if (take) { s[r] = os; id[r] = oi; }                                   \
      }                                                                        \
    }
  { bool dd = (lane & 1) != 0; CE2(dd); }
  #pragma unroll
  for (int K = 4; K <= 128; K <<= 1) {
    bool dd = (lane & (K >> 1)) != 0;
    #pragma unroll
    for (int L = K >> 2; L >= 1; L >>= 1) CROSS2(L, dd);
    CE2(dd);
  }
  #undef CE2
  #undef CROSS2
  float smax = __shfl(s[0], 0, 64);
  float e0 = 0.f, e1 = 0.f;
  if (lane < 16) { e0 = expf(s[0] - smax); e1 = expf(s[1] - smax); }
  float part = e0 + e1;
  #pragma unroll
  for (int m = 1; m < 16; m <<= 1) part += __shfl_xor(part, m, 64);
  if (lane < 16) {
    int f0 = id[0], f1 = id[1];
    int vi0 = s1i[bx + (f0 >> 5)] * NKEYS + s1i[by + (f0 & 31)];
    int vi1 = s1i[bx + (f1 >> 5)] * NKEYS + s1i[by + (f1 & 31)];
    wgt[(size_t)th * KSEL + lane * 2] = e0 / part;
    wgt[(size_t)th * KSEL + lane * 2 + 1] = e1 / part;
    vidx[(size_t)th * KSEL + lane * 2] = vi0;
    vidx[(size_t)th * KSEL + lane * 2 + 1] = vi1;
  }
}

// ---------------- fallback fp32 gather (for small ws) ----------------
__global__ __launch_bounds__(256) void gather_kernel(
    const float* __restrict__ wgt, const int* __restrict__ vidx,
    const float* __restrict__ values, float* __restrict__ out) {
  const int tp = blockIdx.x;
  const int tid = threadIdx.x;
  __shared__ float ws_[512];
  __shared__ int vs_[512];
  ws_[tid] = wgt[(size_t)tp * 512 + tid];
  ws_[tid + 256] = wgt[(size_t)tp * 512 + tid + 256];
  vs_[tid] = vidx[(size_t)tp * 512 + tid];
  vs_[tid + 256] = vidx[(size_t)tp * 512 + tid + 256];
  __syncthreads();
  const int sub = tid >> 7;
  const int c4 = (tid & 127) * 4;
  const float* wp = &ws_[sub * 256];
  const int* vp = &vs_[sub * 256];
  float4 a = make_float4(0.f, 0.f, 0.f, 0.f);
  #pragma unroll 4
  for (int e = 0; e < 256; ++e) {
    float4 vv = *(const float4*)(values + (size_t)vp[e] * CDIM + c4);
    float wv = wp[e];
    a.x += wv * vv.x; a.y += wv * vv.y; a.z += wv * vv.z; a.w += wv * vv.w;
  }
  *(float4*)(out + (size_t)(tp * 2 + sub) * CDIM + c4) = a;
}

extern "C" void kernel_launch(void* const* d_in, const int* in_sizes, int n_in,
                              void* d_out, int out_size, void* d_ws, size_t ws_size,
                              hipStream_t stream) {
  const float* X      = (const float*)d_in[0];
  const float* W      = (const float*)d_in[1];
  const float* keys   = (const float*)d_in[2];
  const float* values = (const float*)d_in[3];
  const float* gamma  = (const float*)d_in[4];
  const float* beta   = (const float*)d_in[5];
  char* ws = (char*)d_ws;

  if (ws_size >= (92u << 20)) {
    // fused layout: vbf does NOT alias Q/kT (convert runs concurrent with qgemm)
    float* s1s = (float*)(ws);                  // 0..4 MB
    int*   s1i = (int*)  (ws + (4u << 20));     // 4..8 MB
    float* kT  = (float*)(ws + (8u << 20));     // 8..10 MB
    unsigned int* vbf = (unsigned int*)(ws + (12u << 20));  // 12..76 MB
    float* Q   = (float*)(ws + (76u << 20));    // 76..92 MB
    fused_pre<<<16960, 256, 0, stream>>>(X, W, gamma, beta, Q, keys, kT, values, vbf);
    dots_sel<<<dim3(16, 64), 512, 0, stream>>>(Q, kT, s1s, s1i);
    stage2_gather<<<2048, 256, 0, stream>>>(s1s, s1i, (const unsigned short*)vbf, (float*)d_out);
  } else {
    // sequential r10 layout (vbf overlaps dead Q+kT)
    float* s1s = (float*)(ws);                  // 0..4 MB
    int*   s1i = (int*)  (ws + (4u << 20));     // 4..8 MB
    float* wgt = (float*)(ws + (8u << 20));     // 8..10 MB (fp32 path only)
    int*   vix = (int*)  (ws + (10u << 20));    // 10..12 MB (fp32 path only)
    float* Q   = (float*)(ws + (12u << 20));    // 12..28 MB (dead after dots_sel)
    float* kT  = (float*)(ws + (28u << 20));    // 28..30 MB (dead after dots_sel)
    unsigned int* vbf = (unsigned int*)(ws + (12u << 20));  // 12..76 MB (overlaps dead Q+kT)
    const bool bf16_path = ws_size >= (76u << 20);
    transpose_keys<<<dim3(16, 4), 256, 0, stream>>>(keys, kT);
    qgemm_ln<<<dim3(32, 16), 256, 0, stream>>>(X, W, gamma, beta, Q);
    dots_sel<<<dim3(16, 64), 512, 0, stream>>>(Q, kT, s1s, s1i);
    if (bf16_path) {
      convert_values<<<16384, 256, 0, stream>>>(values, vbf);
      stage2_gather<<<2048, 256, 0, stream>>>(s1s, s1i, (const unsigned short*)vbf, (float*)d_out);
    } else {
      stage2_kernel<<<4096, 256, 0, stream>>>(s1s, s1i, wgt, vix);
      gather_kernel<<<1024, 256, 0, stream>>>(wgt, vix, values, (float*)d_out);
    }
  }
}